// Round 1
// baseline (783.674 us; speedup 1.0000x reference)
//
#include <hip/hip_runtime.h>

#define SEQ    2048
#define BATCH  2
#define NHQ    32
#define NHKV   8
#define DHEAD  128
#define QSCALE 0.08838834764831845f   // 1/sqrt(128)

typedef __fp16 f16;
typedef f16 f16x2 __attribute__((ext_vector_type(2)));
typedef f16 f16x4 __attribute__((ext_vector_type(4)));
typedef f16 f16x8 __attribute__((ext_vector_type(8)));
typedef float f32x4 __attribute__((ext_vector_type(4)));

#define KSTRIDE 136                 // halfs per K-tile row (128 + 8 pad)
#define VSTRIDE 40                  // halfs per Vt row (32 k + 8 pad; 16B-aligned rows)
#define KBUF    (32 * KSTRIDE)      // 4352 halfs
#define VBUF    (128 * VSTRIDE)     // 5120 halfs

// v2 structure:
//  * 8 waves x 16 q-rows = 128 q-rows/block share each staged K/V tile
//    (staging + barrier + K/V fetch per output HALVED vs 4-wave blocks).
//  * V staged column-wise: lane owns one d, walks k -> coalesced global
//    loads (64 consecutive floats/wave) and a single contiguous f16x8
//    LDS write per thread. Replaces 16 scalar b16 writes at 4-way bank
//    conflict (the 3.47e7 SQ_LDS_BANK_CONFLICT source) with conflict-free
//    b128 writes.
//  * VSTRIDE 40 (80B rows): 16B-aligned rows -> PV reads are real
//    ds_read_b64 (f16x4), bank-spread 20*lane mod 32 (min-cycle).
//  * Direct-from-register epilogue: same 16x64B store segments as the old
//    LDS-transpose epilogue, zero LDS traffic.
//  * Defer-max online softmax: skip O-rescale unless any row max grows >8
//    (P bounded by e^8, safe in f16; first tile forces the rescale path).
__global__ __launch_bounds__(512, 6) void attn_fwd(const float* __restrict__ Q,
                                                   const float* __restrict__ K,
                                                   const float* __restrict__ V,
                                                   float* __restrict__ O) {
  const int qt  = gridDim.x - 1 - blockIdx.x;   // heavy (large-qt) blocks first
  const int bh  = blockIdx.y;
  const int b   = bh >> 5;
  const int hq  = bh & 31;
  const int hkv = hq >> 2;
  const int t    = threadIdx.x;
  const int wave = t >> 6;
  const int lane = t & 63;
  const int col  = lane & 15;
  const int quad = lane >> 4;

  const int q_base = qt * 128 + wave * 16;
  const int qrs = BATCH * NHQ * DHEAD;    // 8192
  const int krs = BATCH * NHKV * DHEAD;   // 2048

  const float* Qp = Q + ((size_t)b * NHQ  + hq ) * DHEAD;
  const float* Kp = K + ((size_t)b * NHKV + hkv) * DHEAD;
  const float* Vp = V + ((size_t)b * NHKV + hkv) * DHEAD;
  float*       Op = O + ((size_t)b * NHQ  + hq ) * DHEAD;

  __shared__ __align__(16) f16 smem[2 * KBUF + 2 * VBUF];  // 37888 B -> 4 blocks/CU

  // ---- Q fragments (B-operand of 16x16x32: B[n=col][k=quad*8+j]), pre-scaled ----
  f16x8 qf[4];
  {
    const float* qsrc = Qp + (size_t)(q_base + col) * qrs + quad * 8;
    #pragma unroll
    for (int c = 0; c < 4; ++c) {
      float4 a = *(const float4*)(qsrc + c * 32);
      float4 e = *(const float4*)(qsrc + c * 32 + 4);
      f16x2 p0 = __builtin_amdgcn_cvt_pkrtz(a.x * QSCALE, a.y * QSCALE);
      f16x2 p1 = __builtin_amdgcn_cvt_pkrtz(a.z * QSCALE, a.w * QSCALE);
      f16x2 p2 = __builtin_amdgcn_cvt_pkrtz(e.x * QSCALE, e.y * QSCALE);
      f16x2 p3 = __builtin_amdgcn_cvt_pkrtz(e.z * QSCALE, e.w * QSCALE);
      qf[c][0] = p0[0]; qf[c][1] = p0[1]; qf[c][2] = p1[0]; qf[c][3] = p1[1];
      qf[c][4] = p2[0]; qf[c][5] = p2[1]; qf[c][6] = p3[0]; qf[c][7] = p3[1];
    }
  }

  f32x4 oacc[8];
  #pragma unroll
  for (int h = 0; h < 8; ++h) oacc[h] = (f32x4){0.f, 0.f, 0.f, 0.f};
  float m_i = -__builtin_inff();
  float l_i = 0.f;

  const int nt_blk = 4 * qt + 4;                // block-uniform trip count
  const int nt_w   = 4 * qt + (wave >> 1) + 1;  // this wave's causal tiles

  // staging coords: K rows via float4 (512 thr -> 8 floats each),
  // V via d-columns (lane=d, walk k) -> transposed write is contiguous
  const int ktk = t >> 5;            // 0..15 (+16 for second row)
  const int ktd = (t & 31) * 4;
  const int vd  = t & 127;           // Vt row (d)
  const int vh  = t >> 7;            // 0..3 -> which k-octet

  float4 kr[2];
  float  vf[8];

  // prologue: global loads for tile 0
  #pragma unroll
  for (int ro = 0; ro < 2; ++ro)
    kr[ro] = *(const float4*)(Kp + (size_t)(ktk + ro * 16) * krs + ktd);
  #pragma unroll
  for (int i = 0; i < 8; ++i)
    vf[i] = Vp[(size_t)(vh * 8 + i) * krs + vd];

  for (int kt = 0; kt < nt_blk; ++kt) {
    const int bf = kt & 1;
    f16* kb = smem + bf * KBUF;
    f16* vb = smem + 2 * KBUF + bf * VBUF;

    // ---- stage tile kt from registers (cvt + vectorized LDS writes) ----
    #pragma unroll
    for (int ro = 0; ro < 2; ++ro) {
      f16x2 lo = __builtin_amdgcn_cvt_pkrtz(kr[ro].x, kr[ro].y);
      f16x2 hi = __builtin_amdgcn_cvt_pkrtz(kr[ro].z, kr[ro].w);
      f16x4 v4; v4[0] = lo[0]; v4[1] = lo[1]; v4[2] = hi[0]; v4[3] = hi[1];
      *(f16x4*)(kb + (ktk + ro * 16) * KSTRIDE + ktd) = v4;
    }
    {
      f16x2 p0 = __builtin_amdgcn_cvt_pkrtz(vf[0], vf[1]);
      f16x2 p1 = __builtin_amdgcn_cvt_pkrtz(vf[2], vf[3]);
      f16x2 p2 = __builtin_amdgcn_cvt_pkrtz(vf[4], vf[5]);
      f16x2 p3 = __builtin_amdgcn_cvt_pkrtz(vf[6], vf[7]);
      f16x8 v8;
      v8[0] = p0[0]; v8[1] = p0[1]; v8[2] = p1[0]; v8[3] = p1[1];
      v8[4] = p2[0]; v8[5] = p2[1]; v8[6] = p3[0]; v8[7] = p3[1];
      *(f16x8*)(vb + vd * VSTRIDE + vh * 8) = v8;   // Vt[d][k-octet], 16B aligned
    }

    // ---- issue next tile's global loads (latency hides under compute) ----
    if (kt + 1 < nt_blk) {
      const int k0n = (kt + 1) * 32;
      #pragma unroll
      for (int ro = 0; ro < 2; ++ro)
        kr[ro] = *(const float4*)(Kp + (size_t)(k0n + ktk + ro * 16) * krs + ktd);
      #pragma unroll
      for (int i = 0; i < 8; ++i)
        vf[i] = Vp[(size_t)(k0n + vh * 8 + i) * krs + vd];
    }

    __syncthreads();

    if (kt < nt_w) {
      const int k0 = kt * 32;

      // ---- S^T = K Q^T : A = K rows (m=k), B = Q (n=q) ----
      f32x4 s0 = {0.f, 0.f, 0.f, 0.f}, s1 = {0.f, 0.f, 0.f, 0.f};
      #pragma unroll
      for (int c = 0; c < 4; ++c) {
        f16x8 ka = *(const f16x8*)(kb + col * KSTRIDE + quad * 8 + c * 32);
        s0 = __builtin_amdgcn_mfma_f32_16x16x32_f16(ka, qf[c], s0, 0, 0, 0);
      }
      #pragma unroll
      for (int c = 0; c < 4; ++c) {
        f16x8 ka = *(const f16x8*)(kb + (16 + col) * KSTRIDE + quad * 8 + c * 32);
        s1 = __builtin_amdgcn_mfma_f32_16x16x32_f16(ka, qf[c], s1, 0, 0, 0);
      }

      // ---- causal mask (only final tiles); q = col, k = quad*4+r ----
      const int qrow = q_base + col;
      if (k0 + 31 > q_base) {
        #pragma unroll
        for (int r = 0; r < 4; ++r) {
          if (k0 + quad * 4 + r      > qrow) s0[r] = -__builtin_inff();
          if (k0 + 16 + quad * 4 + r > qrow) s1[r] = -__builtin_inff();
        }
      }

      // ---- online softmax with defer-max (T13, THR=8) ----
      float mx = fmaxf(fmaxf(fmaxf(s0[0], s0[1]), fmaxf(s0[2], s0[3])),
                       fmaxf(fmaxf(s1[0], s1[1]), fmaxf(s1[2], s1[3])));
      mx = fmaxf(mx, __shfl_xor(mx, 16, 64));
      mx = fmaxf(mx, __shfl_xor(mx, 32, 64));

      if (!__all(mx - m_i <= 8.0f)) {   // first tile: +inf -> rescale path
        const float mnew  = fmaxf(m_i, mx);
        const float alpha = __expf(m_i - mnew);   // first tile: exp(-inf)=0
        m_i = mnew;
        l_i *= alpha;
        #pragma unroll
        for (int h = 0; h < 8; ++h) {
          oacc[h][0] *= alpha; oacc[h][1] *= alpha;
          oacc[h][2] *= alpha; oacc[h][3] *= alpha;
        }
      }

      float e0[4], e1[4], rs = 0.f;
      #pragma unroll
      for (int r = 0; r < 4; ++r) {
        e0[r] = __expf(s0[r] - m_i);
        e1[r] = __expf(s1[r] - m_i);
        rs += e0[r] + e1[r];
      }
      rs += __shfl_xor(rs, 16, 64);
      rs += __shfl_xor(rs, 32, 64);
      l_i += rs;

      // ---- P^T already in 16x16x16 B-operand layout ----
      f16x2 a01 = __builtin_amdgcn_cvt_pkrtz(e0[0], e0[1]);
      f16x2 a23 = __builtin_amdgcn_cvt_pkrtz(e0[2], e0[3]);
      f16x2 b01 = __builtin_amdgcn_cvt_pkrtz(e1[0], e1[1]);
      f16x2 b23 = __builtin_amdgcn_cvt_pkrtz(e1[2], e1[3]);
      f16x4 pb0; pb0[0] = a01[0]; pb0[1] = a01[1]; pb0[2] = a23[0]; pb0[3] = a23[1];
      f16x4 pb1; pb1[0] = b01[0]; pb1[1] = b01[1]; pb1[2] = b23[0]; pb1[3] = b23[1];

      // ---- O^T += V^T P^T  (A = V^T rows from Vt LDS, 8B-aligned f16x4) ----
      #pragma unroll
      for (int h = 0; h < 8; ++h) {
        const f16* vr = vb + (h * 16 + col) * VSTRIDE + quad * 4;
        f16x4 va0 = *(const f16x4*)(vr);
        f16x4 va1 = *(const f16x4*)(vr + 16);
        oacc[h] = __builtin_amdgcn_mfma_f32_16x16x16f16(va0, pb0, oacc[h], 0, 0, 0);
        oacc[h] = __builtin_amdgcn_mfma_f32_16x16x16f16(va1, pb1, oacc[h], 0, 0, 0);
      }
    }
  }

  // ---- epilogue: direct stores (16 x 64B segments per instr, same as the
  //      old LDS-transpose path, but zero LDS traffic) ----
  {
    const float invl = 1.0f / l_i;
    #pragma unroll
    for (int h = 0; h < 8; ++h) {
      float4 o;
      o.x = oacc[h][0] * invl; o.y = oacc[h][1] * invl;
      o.z = oacc[h][2] * invl; o.w = oacc[h][3] * invl;
      *(float4*)(Op + (size_t)(q_base + col) * qrs + h * 16 + quad * 4) = o;
    }
  }
}

extern "C" void kernel_launch(void* const* d_in, const int* in_sizes, int n_in,
                              void* d_out, int out_size, void* d_ws, size_t ws_size,
                              hipStream_t stream) {
  const float* Q = (const float*)d_in[0];
  const float* K = (const float*)d_in[1];
  const float* V = (const float*)d_in[2];
  float* O = (float*)d_out;
  (void)in_sizes; (void)n_in; (void)out_size; (void)d_ws; (void)ws_size;
  dim3 grid(SEQ / 128, BATCH * NHQ);
  attn_fwd<<<grid, dim3(512), 0, stream>>>(Q, K, V, O);
}

// Round 2
// 360.834 us; speedup vs baseline: 2.1718x; 2.1718x over previous
//
#include <hip/hip_runtime.h>

#define SEQ    2048
#define BATCH  2
#define NHQ    32
#define NHKV   8
#define DHEAD  128
#define QSCALE 0.08838834764831845f   // 1/sqrt(128)

typedef __fp16 f16;
typedef f16 f16x2 __attribute__((ext_vector_type(2)));
typedef f16 f16x4 __attribute__((ext_vector_type(4)));
typedef f16 f16x8 __attribute__((ext_vector_type(8)));
typedef float f32x4 __attribute__((ext_vector_type(4)));

#define KSTRIDE 136                 // halfs per K-tile row (128 + 8 pad)
#define VSTRIDE 40                  // halfs per Vt row (32 k + 8 pad; 16B-aligned rows)
#define KBUF    (32 * KSTRIDE)      // 4352 halfs
#define VBUF    (128 * VSTRIDE)     // 5120 halfs

// v3 = v2 with the register catastrophe fixed.
// v2 post-mortem: __launch_bounds__(512,6) capped VGPR at ~85; inner-loop
// state (~100 regs: oacc 32 + qf 16 + prefetch 16 + addressing) spilled to
// scratch -> WRITE_SIZE 552 MB (9x output), FETCH +430 MB, 716 us.
// Fix: (512,4) -> 128-VGPR cap, 2 blocks/CU = 16 waves/CU (same wave count
// as the 356 us round-0 config, but each staged K/V tile serves 128 q-rows
// instead of 64: staging instrs, barriers, and K/V refetch per output halved).
__global__ __launch_bounds__(512, 4) void attn_fwd(const float* __restrict__ Q,
                                                   const float* __restrict__ K,
                                                   const float* __restrict__ V,
                                                   float* __restrict__ O) {
  const int qt  = gridDim.x - 1 - blockIdx.x;   // heavy (large-qt) blocks first
  const int bh  = blockIdx.y;
  const int b   = bh >> 5;
  const int hq  = bh & 31;
  const int hkv = hq >> 2;
  const int t    = threadIdx.x;
  const int wave = t >> 6;
  const int lane = t & 63;
  const int col  = lane & 15;
  const int quad = lane >> 4;

  const int q_base = qt * 128 + wave * 16;
  const int qrs = BATCH * NHQ * DHEAD;    // 8192
  const int krs = BATCH * NHKV * DHEAD;   // 2048

  const float* Qp = Q + ((size_t)b * NHQ  + hq ) * DHEAD;
  const float* Kp = K + ((size_t)b * NHKV + hkv) * DHEAD;
  const float* Vp = V + ((size_t)b * NHKV + hkv) * DHEAD;
  float*       Op = O + ((size_t)b * NHQ  + hq ) * DHEAD;

  __shared__ __align__(16) f16 smem[2 * KBUF + 2 * VBUF];  // 37888 B

  // ---- Q fragments (B-operand of 16x16x32: B[n=col][k=quad*8+j]), pre-scaled ----
  f16x8 qf[4];
  {
    const float* qsrc = Qp + (size_t)(q_base + col) * qrs + quad * 8;
    #pragma unroll
    for (int c = 0; c < 4; ++c) {
      float4 a = *(const float4*)(qsrc + c * 32);
      float4 e = *(const float4*)(qsrc + c * 32 + 4);
      f16x2 p0 = __builtin_amdgcn_cvt_pkrtz(a.x * QSCALE, a.y * QSCALE);
      f16x2 p1 = __builtin_amdgcn_cvt_pkrtz(a.z * QSCALE, a.w * QSCALE);
      f16x2 p2 = __builtin_amdgcn_cvt_pkrtz(e.x * QSCALE, e.y * QSCALE);
      f16x2 p3 = __builtin_amdgcn_cvt_pkrtz(e.z * QSCALE, e.w * QSCALE);
      qf[c][0] = p0[0]; qf[c][1] = p0[1]; qf[c][2] = p1[0]; qf[c][3] = p1[1];
      qf[c][4] = p2[0]; qf[c][5] = p2[1]; qf[c][6] = p3[0]; qf[c][7] = p3[1];
    }
  }

  f32x4 oacc[8];
  #pragma unroll
  for (int h = 0; h < 8; ++h) oacc[h] = (f32x4){0.f, 0.f, 0.f, 0.f};
  float m_i = -__builtin_inff();
  float l_i = 0.f;

  const int nt_blk = 4 * qt + 4;                // block-uniform trip count
  const int nt_w   = 4 * qt + (wave >> 1) + 1;  // this wave's causal tiles

  // staging coords: K rows via float4 (512 thr -> 8 floats each),
  // V via d-columns (lane=d, walk k) -> transposed write is contiguous
  const int ktk = t >> 5;            // 0..15 (+16 for second row)
  const int ktd = (t & 31) * 4;
  const int vd  = t & 127;           // Vt row (d)
  const int vh  = t >> 7;            // 0..3 -> which k-octet

  float4 kr[2];
  float  vf[8];

  // prologue: global loads for tile 0
  #pragma unroll
  for (int ro = 0; ro < 2; ++ro)
    kr[ro] = *(const float4*)(Kp + (size_t)(ktk + ro * 16) * krs + ktd);
  #pragma unroll
  for (int i = 0; i < 8; ++i)
    vf[i] = Vp[(size_t)(vh * 8 + i) * krs + vd];

  for (int kt = 0; kt < nt_blk; ++kt) {
    const int bf = kt & 1;
    f16* kb = smem + bf * KBUF;
    f16* vb = smem + 2 * KBUF + bf * VBUF;

    // ---- stage tile kt from registers (cvt + vectorized LDS writes) ----
    #pragma unroll
    for (int ro = 0; ro < 2; ++ro) {
      f16x2 lo = __builtin_amdgcn_cvt_pkrtz(kr[ro].x, kr[ro].y);
      f16x2 hi = __builtin_amdgcn_cvt_pkrtz(kr[ro].z, kr[ro].w);
      f16x4 v4; v4[0] = lo[0]; v4[1] = lo[1]; v4[2] = hi[0]; v4[3] = hi[1];
      *(f16x4*)(kb + (ktk + ro * 16) * KSTRIDE + ktd) = v4;
    }
    {
      f16x2 p0 = __builtin_amdgcn_cvt_pkrtz(vf[0], vf[1]);
      f16x2 p1 = __builtin_amdgcn_cvt_pkrtz(vf[2], vf[3]);
      f16x2 p2 = __builtin_amdgcn_cvt_pkrtz(vf[4], vf[5]);
      f16x2 p3 = __builtin_amdgcn_cvt_pkrtz(vf[6], vf[7]);
      f16x8 v8;
      v8[0] = p0[0]; v8[1] = p0[1]; v8[2] = p1[0]; v8[3] = p1[1];
      v8[4] = p2[0]; v8[5] = p2[1]; v8[6] = p3[0]; v8[7] = p3[1];
      *(f16x8*)(vb + vd * VSTRIDE + vh * 8) = v8;   // Vt[d][k-octet], 16B aligned
    }

    // ---- issue next tile's global loads (latency hides under compute) ----
    if (kt + 1 < nt_blk) {
      const int k0n = (kt + 1) * 32;
      #pragma unroll
      for (int ro = 0; ro < 2; ++ro)
        kr[ro] = *(const float4*)(Kp + (size_t)(k0n + ktk + ro * 16) * krs + ktd);
      #pragma unroll
      for (int i = 0; i < 8; ++i)
        vf[i] = Vp[(size_t)(k0n + vh * 8 + i) * krs + vd];
    }

    __syncthreads();

    if (kt < nt_w) {
      const int k0 = kt * 32;

      // ---- S^T = K Q^T : A = K rows (m=k), B = Q (n=q) ----
      f32x4 s0 = {0.f, 0.f, 0.f, 0.f}, s1 = {0.f, 0.f, 0.f, 0.f};
      #pragma unroll
      for (int c = 0; c < 4; ++c) {
        f16x8 ka = *(const f16x8*)(kb + col * KSTRIDE + quad * 8 + c * 32);
        s0 = __builtin_amdgcn_mfma_f32_16x16x32_f16(ka, qf[c], s0, 0, 0, 0);
      }
      #pragma unroll
      for (int c = 0; c < 4; ++c) {
        f16x8 ka = *(const f16x8*)(kb + (16 + col) * KSTRIDE + quad * 8 + c * 32);
        s1 = __builtin_amdgcn_mfma_f32_16x16x32_f16(ka, qf[c], s1, 0, 0, 0);
      }

      // ---- causal mask (only final tiles); q = col, k = quad*4+r ----
      const int qrow = q_base + col;
      if (k0 + 31 > q_base) {
        #pragma unroll
        for (int r = 0; r < 4; ++r) {
          if (k0 + quad * 4 + r      > qrow) s0[r] = -__builtin_inff();
          if (k0 + 16 + quad * 4 + r > qrow) s1[r] = -__builtin_inff();
        }
      }

      // ---- online softmax with defer-max (T13, THR=8) ----
      float mx = fmaxf(fmaxf(fmaxf(s0[0], s0[1]), fmaxf(s0[2], s0[3])),
                       fmaxf(fmaxf(s1[0], s1[1]), fmaxf(s1[2], s1[3])));
      mx = fmaxf(mx, __shfl_xor(mx, 16, 64));
      mx = fmaxf(mx, __shfl_xor(mx, 32, 64));

      if (!__all(mx - m_i <= 8.0f)) {   // first tile: +inf -> rescale path
        const float mnew  = fmaxf(m_i, mx);
        const float alpha = __expf(m_i - mnew);   // first tile: exp(-inf)=0
        m_i = mnew;
        l_i *= alpha;
        #pragma unroll
        for (int h = 0; h < 8; ++h) {
          oacc[h][0] *= alpha; oacc[h][1] *= alpha;
          oacc[h][2] *= alpha; oacc[h][3] *= alpha;
        }
      }

      float e0[4], e1[4], rs = 0.f;
      #pragma unroll
      for (int r = 0; r < 4; ++r) {
        e0[r] = __expf(s0[r] - m_i);
        e1[r] = __expf(s1[r] - m_i);
        rs += e0[r] + e1[r];
      }
      rs += __shfl_xor(rs, 16, 64);
      rs += __shfl_xor(rs, 32, 64);
      l_i += rs;

      // ---- P^T already in 16x16x16 B-operand layout ----
      f16x2 a01 = __builtin_amdgcn_cvt_pkrtz(e0[0], e0[1]);
      f16x2 a23 = __builtin_amdgcn_cvt_pkrtz(e0[2], e0[3]);
      f16x2 b01 = __builtin_amdgcn_cvt_pkrtz(e1[0], e1[1]);
      f16x2 b23 = __builtin_amdgcn_cvt_pkrtz(e1[2], e1[3]);
      f16x4 pb0; pb0[0] = a01[0]; pb0[1] = a01[1]; pb0[2] = a23[0]; pb0[3] = a23[1];
      f16x4 pb1; pb1[0] = b01[0]; pb1[1] = b01[1]; pb1[2] = b23[0]; pb1[3] = b23[1];

      // ---- O^T += V^T P^T  (A = V^T rows from Vt LDS, 8B-aligned f16x4) ----
      #pragma unroll
      for (int h = 0; h < 8; ++h) {
        const f16* vr = vb + (h * 16 + col) * VSTRIDE + quad * 4;
        f16x4 va0 = *(const f16x4*)(vr);
        f16x4 va1 = *(const f16x4*)(vr + 16);
        oacc[h] = __builtin_amdgcn_mfma_f32_16x16x16f16(va0, pb0, oacc[h], 0, 0, 0);
        oacc[h] = __builtin_amdgcn_mfma_f32_16x16x16f16(va1, pb1, oacc[h], 0, 0, 0);
      }
    }
  }

  // ---- epilogue: direct stores (16 x 64B segments per instr) ----
  {
    const float invl = 1.0f / l_i;
    #pragma unroll
    for (int h = 0; h < 8; ++h) {
      float4 o;
      o.x = oacc[h][0] * invl; o.y = oacc[h][1] * invl;
      o.z = oacc[h][2] * invl; o.w = oacc[h][3] * invl;
      *(float4*)(Op + (size_t)(q_base + col) * qrs + h * 16 + quad * 4) = o;
    }
  }
}

extern "C" void kernel_launch(void* const* d_in, const int* in_sizes, int n_in,
                              void* d_out, int out_size, void* d_ws, size_t ws_size,
                              hipStream_t stream) {
  const float* Q = (const float*)d_in[0];
  const float* K = (const float*)d_in[1];
  const float* V = (const float*)d_in[2];
  float* O = (float*)d_out;
  (void)in_sizes; (void)n_in; (void)out_size; (void)d_ws; (void)ws_size;
  dim3 grid(SEQ / 128, BATCH * NHQ);
  attn_fwd<<<grid, dim3(512), 0, stream>>>(Q, K, V, O);
}

// Round 4
// 258.724 us; speedup vs baseline: 3.0290x; 1.3947x over previous
//
#include <hip/hip_runtime.h>

#define SEQ    2048
#define BATCH  2
#define NHQ    32
#define NHKV   8
#define DHEAD  128
#define QSCALE 0.08838834764831845f   // 1/sqrt(128)

typedef __fp16 f16;
typedef f16 f16x2 __attribute__((ext_vector_type(2)));
typedef f16 f16x4 __attribute__((ext_vector_type(4)));
typedef f16 f16x8 __attribute__((ext_vector_type(8)));
typedef float f32x4 __attribute__((ext_vector_type(4)));

#define KSTRIDE 136                 // halfs per K-tile row (128 + 8 pad)
#define VSTRIDE 40                  // halfs per Vt row (32 k + 8 pad; 16B-aligned rows)
#define KBUF    (32 * KSTRIDE)      // 4352 halfs
#define VBUF    (128 * VSTRIDE)     // 5120 halfs

// v4 (resubmit — round 3 failed on container infra, no GPU verdict).
// v3 post-mortem: block cost = 4*qt+4 tile-units (16:1 spread). With 1024
// blocks linearized l = bh*16+i, the blocks landing on one CU (l mod 256
// alike) all share the SAME i -> same qt -> 4x identical cost: qt=15 CUs
// carry 256 units vs mean 136 -> wall ~1.9x balanced ideal. Seen as
// OccupancyPercent 22.7 (time-avg), MfmaUtil 14.5.
// Fix: each block processes the q-tile PAIR {15-i, i} sequentially
// (cost 68 units for EVERY block, robust to any block->CU policy).
// Grid 8x64 = 512 blocks = exactly 2/CU. Register state reused across the
// two passes; inter-pass LDS hazard ordered by pass-2's first barrier
// (pass-1 last compute reads buf1; pass-2 stages buf0, barriers, and only
// touches buf1 again at its kt=1 staging — provably race-free).
__global__ __launch_bounds__(512, 4) void attn_fwd(const float* __restrict__ Q,
                                                   const float* __restrict__ K,
                                                   const float* __restrict__ V,
                                                   float* __restrict__ O) {
  const int bh  = blockIdx.y;
  const int b   = bh >> 5;
  const int hq  = bh & 31;
  const int hkv = hq >> 2;
  const int t    = threadIdx.x;
  const int wave = t >> 6;
  const int lane = t & 63;
  const int col  = lane & 15;
  const int quad = lane >> 4;

  const int qrs = BATCH * NHQ * DHEAD;    // 8192
  const int krs = BATCH * NHKV * DHEAD;   // 2048

  const float* Qp = Q + ((size_t)b * NHQ  + hq ) * DHEAD;
  const float* Kp = K + ((size_t)b * NHKV + hkv) * DHEAD;
  const float* Vp = V + ((size_t)b * NHKV + hkv) * DHEAD;
  float*       Op = O + ((size_t)b * NHQ  + hq ) * DHEAD;

  __shared__ __align__(16) f16 smem[2 * KBUF + 2 * VBUF];  // 37888 B

  // staging coords: K rows via float4 (512 thr -> 8 floats each),
  // V via d-columns (lane=d, walk k) -> transposed write is contiguous
  const int ktk = t >> 5;            // 0..15 (+16 for second row)
  const int ktd = (t & 31) * 4;
  const int vd  = t & 127;           // Vt row (d)
  const int vh  = t >> 7;            // 0..3 -> which k-octet

  #pragma unroll 1
  for (int pass = 0; pass < 2; ++pass) {
    // heavy tile first; pair sums to 15 -> all blocks cost 68 tile-units
    const int qt     = pass ? (int)blockIdx.x : 15 - (int)blockIdx.x;
    const int q_base = qt * 128 + wave * 16;

    // ---- Q fragments (B-operand of 16x16x32: B[n=col][k=quad*8+j]), pre-scaled ----
    f16x8 qf[4];
    {
      const float* qsrc = Qp + (size_t)(q_base + col) * qrs + quad * 8;
      #pragma unroll
      for (int c = 0; c < 4; ++c) {
        float4 a = *(const float4*)(qsrc + c * 32);
        float4 e = *(const float4*)(qsrc + c * 32 + 4);
        f16x2 p0 = __builtin_amdgcn_cvt_pkrtz(a.x * QSCALE, a.y * QSCALE);
        f16x2 p1 = __builtin_amdgcn_cvt_pkrtz(a.z * QSCALE, a.w * QSCALE);
        f16x2 p2 = __builtin_amdgcn_cvt_pkrtz(e.x * QSCALE, e.y * QSCALE);
        f16x2 p3 = __builtin_amdgcn_cvt_pkrtz(e.z * QSCALE, e.w * QSCALE);
        qf[c][0] = p0[0]; qf[c][1] = p0[1]; qf[c][2] = p1[0]; qf[c][3] = p1[1];
        qf[c][4] = p2[0]; qf[c][5] = p2[1]; qf[c][6] = p3[0]; qf[c][7] = p3[1];
      }
    }

    f32x4 oacc[8];
    #pragma unroll
    for (int h = 0; h < 8; ++h) oacc[h] = (f32x4){0.f, 0.f, 0.f, 0.f};
    float m_i = -__builtin_inff();
    float l_i = 0.f;

    const int nt_blk = 4 * qt + 4;                // block-uniform trip count
    const int nt_w   = 4 * qt + (wave >> 1) + 1;  // this wave's causal tiles

    float4 kr[2];
    float  vf[8];

    // prologue: global loads for tile 0
    #pragma unroll
    for (int ro = 0; ro < 2; ++ro)
      kr[ro] = *(const float4*)(Kp + (size_t)(ktk + ro * 16) * krs + ktd);
    #pragma unroll
    for (int i = 0; i < 8; ++i)
      vf[i] = Vp[(size_t)(vh * 8 + i) * krs + vd];

    for (int kt = 0; kt < nt_blk; ++kt) {
      const int bf = kt & 1;
      f16* kb = smem + bf * KBUF;
      f16* vb = smem + 2 * KBUF + bf * VBUF;

      // ---- stage tile kt from registers (cvt + vectorized LDS writes) ----
      #pragma unroll
      for (int ro = 0; ro < 2; ++ro) {
        f16x2 lo = __builtin_amdgcn_cvt_pkrtz(kr[ro].x, kr[ro].y);
        f16x2 hi = __builtin_amdgcn_cvt_pkrtz(kr[ro].z, kr[ro].w);
        f16x4 v4; v4[0] = lo[0]; v4[1] = lo[1]; v4[2] = hi[0]; v4[3] = hi[1];
        *(f16x4*)(kb + (ktk + ro * 16) * KSTRIDE + ktd) = v4;
      }
      {
        f16x2 p0 = __builtin_amdgcn_cvt_pkrtz(vf[0], vf[1]);
        f16x2 p1 = __builtin_amdgcn_cvt_pkrtz(vf[2], vf[3]);
        f16x2 p2 = __builtin_amdgcn_cvt_pkrtz(vf[4], vf[5]);
        f16x2 p3 = __builtin_amdgcn_cvt_pkrtz(vf[6], vf[7]);
        f16x8 v8;
        v8[0] = p0[0]; v8[1] = p0[1]; v8[2] = p1[0]; v8[3] = p1[1];
        v8[4] = p2[0]; v8[5] = p2[1]; v8[6] = p3[0]; v8[7] = p3[1];
        *(f16x8*)(vb + vd * VSTRIDE + vh * 8) = v8;   // Vt[d][k-octet], 16B aligned
      }

      // ---- issue next tile's global loads (latency hides under compute) ----
      if (kt + 1 < nt_blk) {
        const int k0n = (kt + 1) * 32;
        #pragma unroll
        for (int ro = 0; ro < 2; ++ro)
          kr[ro] = *(const float4*)(Kp + (size_t)(k0n + ktk + ro * 16) * krs + ktd);
        #pragma unroll
        for (int i = 0; i < 8; ++i)
          vf[i] = Vp[(size_t)(k0n + vh * 8 + i) * krs + vd];
      }

      __syncthreads();

      if (kt < nt_w) {
        const int k0 = kt * 32;

        // ---- S^T = K Q^T : A = K rows (m=k), B = Q (n=q) ----
        f32x4 s0 = {0.f, 0.f, 0.f, 0.f}, s1 = {0.f, 0.f, 0.f, 0.f};
        #pragma unroll
        for (int c = 0; c < 4; ++c) {
          f16x8 ka = *(const f16x8*)(kb + col * KSTRIDE + quad * 8 + c * 32);
          s0 = __builtin_amdgcn_mfma_f32_16x16x32_f16(ka, qf[c], s0, 0, 0, 0);
        }
        #pragma unroll
        for (int c = 0; c < 4; ++c) {
          f16x8 ka = *(const f16x8*)(kb + (16 + col) * KSTRIDE + quad * 8 + c * 32);
          s1 = __builtin_amdgcn_mfma_f32_16x16x32_f16(ka, qf[c], s1, 0, 0, 0);
        }

        // ---- causal mask (only final tiles); q = col, k = quad*4+r ----
        const int qrow = q_base + col;
        if (k0 + 31 > q_base) {
          #pragma unroll
          for (int r = 0; r < 4; ++r) {
            if (k0 + quad * 4 + r      > qrow) s0[r] = -__builtin_inff();
            if (k0 + 16 + quad * 4 + r > qrow) s1[r] = -__builtin_inff();
          }
        }

        // ---- online softmax with defer-max (T13, THR=8) ----
        float mx = fmaxf(fmaxf(fmaxf(s0[0], s0[1]), fmaxf(s0[2], s0[3])),
                         fmaxf(fmaxf(s1[0], s1[1]), fmaxf(s1[2], s1[3])));
        mx = fmaxf(mx, __shfl_xor(mx, 16, 64));
        mx = fmaxf(mx, __shfl_xor(mx, 32, 64));

        if (!__all(mx - m_i <= 8.0f)) {   // first tile: +inf -> rescale path
          const float mnew  = fmaxf(m_i, mx);
          const float alpha = __expf(m_i - mnew);   // first tile: exp(-inf)=0
          m_i = mnew;
          l_i *= alpha;
          #pragma unroll
          for (int h = 0; h < 8; ++h) {
            oacc[h][0] *= alpha; oacc[h][1] *= alpha;
            oacc[h][2] *= alpha; oacc[h][3] *= alpha;
          }
        }

        float e0[4], e1[4], rs = 0.f;
        #pragma unroll
        for (int r = 0; r < 4; ++r) {
          e0[r] = __expf(s0[r] - m_i);
          e1[r] = __expf(s1[r] - m_i);
          rs += e0[r] + e1[r];
        }
        rs += __shfl_xor(rs, 16, 64);
        rs += __shfl_xor(rs, 32, 64);
        l_i += rs;

        // ---- P^T already in 16x16x16 B-operand layout ----
        f16x2 a01 = __builtin_amdgcn_cvt_pkrtz(e0[0], e0[1]);
        f16x2 a23 = __builtin_amdgcn_cvt_pkrtz(e0[2], e0[3]);
        f16x2 b01 = __builtin_amdgcn_cvt_pkrtz(e1[0], e1[1]);
        f16x2 b23 = __builtin_amdgcn_cvt_pkrtz(e1[2], e1[3]);
        f16x4 pb0; pb0[0] = a01[0]; pb0[1] = a01[1]; pb0[2] = a23[0]; pb0[3] = a23[1];
        f16x4 pb1; pb1[0] = b01[0]; pb1[1] = b01[1]; pb1[2] = b23[0]; pb1[3] = b23[1];

        // ---- O^T += V^T P^T  (A = V^T rows from Vt LDS, 8B-aligned f16x4) ----
        #pragma unroll
        for (int h = 0; h < 8; ++h) {
          const f16* vr = vb + (h * 16 + col) * VSTRIDE + quad * 4;
          f16x4 va0 = *(const f16x4*)(vr);
          f16x4 va1 = *(const f16x4*)(vr + 16);
          oacc[h] = __builtin_amdgcn_mfma_f32_16x16x16f16(va0, pb0, oacc[h], 0, 0, 0);
          oacc[h] = __builtin_amdgcn_mfma_f32_16x16x16f16(va1, pb1, oacc[h], 0, 0, 0);
        }
      }
    }

    // ---- epilogue: direct stores (16 x 64B segments per instr) ----
    {
      const float invl = 1.0f / l_i;
      #pragma unroll
      for (int h = 0; h < 8; ++h) {
        float4 o;
        o.x = oacc[h][0] * invl; o.y = oacc[h][1] * invl;
        o.z = oacc[h][2] * invl; o.w = oacc[h][3] * invl;
        *(float4*)(Op + (size_t)(q_base + col) * qrs + h * 16 + quad * 4) = o;
      }
    }
  }
}

extern "C" void kernel_launch(void* const* d_in, const int* in_sizes, int n_in,
                              void* d_out, int out_size, void* d_ws, size_t ws_size,
                              hipStream_t stream) {
  const float* Q = (const float*)d_in[0];
  const float* K = (const float*)d_in[1];
  const float* V = (const float*)d_in[2];
  float* O = (float*)d_out;
  (void)in_sizes; (void)n_in; (void)out_size; (void)d_ws; (void)ws_size;
  dim3 grid(SEQ / 256, BATCH * NHQ);   // 8 x 64: each block does q-tiles {15-i, i}
  attn_fwd<<<grid, dim3(512), 0, stream>>>(Q, K, V, O);
}

// Round 5
// 245.152 us; speedup vs baseline: 3.1967x; 1.0554x over previous
//
#include <hip/hip_runtime.h>

#define SEQ    2048
#define BATCH  2
#define NHQ    32
#define NHKV   8
#define DHEAD  128
// 1/sqrt(128) * log2(e): QK^T logits produced directly in log2 domain,
// so softmax uses raw v_exp_f32 (exp2) with no per-score multiply.
#define QSCALE2 0.12751743f

typedef __fp16 f16;
typedef f16 f16x2 __attribute__((ext_vector_type(2)));
typedef f16 f16x4 __attribute__((ext_vector_type(4)));
typedef f16 f16x8 __attribute__((ext_vector_type(8)));
typedef float f32x4 __attribute__((ext_vector_type(4)));

#define KSTRIDE 136                 // halfs per K-tile row (128 + 8 pad)
#define VSTRIDE 40                  // halfs per Vt row (32 k + 8 pad; 16B-aligned rows)
#define KBUF    (32 * KSTRIDE)      // 4352 halfs
#define VBUF    (128 * VSTRIDE)     // 5120 halfs

static __device__ __forceinline__ float fast_exp2(float x) {
#if __has_builtin(__builtin_amdgcn_exp2f)
  return __builtin_amdgcn_exp2f(x);
#else
  return __builtin_exp2f(x);
#endif
}

// v5 = v4 + PV as 16x16x32 (half the PV MFMAs) + exp2-domain softmax.
// Trick: K kv-row k is staged at LDS row inv(k) = ((k>>2)&1)*16 + (k>>3)*4
// + (k&3)  (bijective, write-side only, loop-invariant addressing). The
// UNCHANGED QK^T read pattern then yields S^T with lane-local k =
// quad*8+r (s0) / quad*8+4+r (s1), which is exactly the f16x8 B-operand
// k-order of mfma_f32_16x16x32_f16 -> PV needs 8 MFMA + 8 ds_read_b128
// (Vt rows contiguous, bank-uniform: window (5*(col%8)+quad)%8) instead
// of 16 MFMA + 16 ds_read_b64. Causal mask indices updated to match.
// v4 history: uniform-cost q-tile pairs {15-i,i} (load balance), 8-wave
// blocks (staging amortization), conflict-free V column staging,
// direct epilogue, defer-max. 177 us at round 4.
__global__ __launch_bounds__(512, 4) void attn_fwd(const float* __restrict__ Q,
                                                   const float* __restrict__ K,
                                                   const float* __restrict__ V,
                                                   float* __restrict__ O) {
  const int bh  = blockIdx.y;
  const int b   = bh >> 5;
  const int hq  = bh & 31;
  const int hkv = hq >> 2;
  const int t    = threadIdx.x;
  const int wave = t >> 6;
  const int lane = t & 63;
  const int col  = lane & 15;
  const int quad = lane >> 4;

  const int qrs = BATCH * NHQ * DHEAD;    // 8192
  const int krs = BATCH * NHKV * DHEAD;   // 2048

  const float* Qp = Q + ((size_t)b * NHQ  + hq ) * DHEAD;
  const float* Kp = K + ((size_t)b * NHKV + hkv) * DHEAD;
  const float* Vp = V + ((size_t)b * NHKV + hkv) * DHEAD;
  float*       Op = O + ((size_t)b * NHQ  + hq ) * DHEAD;

  __shared__ __align__(16) f16 smem[2 * KBUF + 2 * VBUF];  // 37888 B

  // staging coords: K rows via float4 (512 thr -> 8 floats each),
  // V via d-columns (lane=d, walk k) -> transposed write is contiguous
  const int ktk = t >> 5;            // kv row 0..15 (+16 for second row)
  const int ktd = (t & 31) * 4;
  const int vd  = t & 127;           // Vt row (d)
  const int vh  = t >> 7;            // 0..3 -> which k-octet
  // permuted LDS row for K staging: row inv(ktk); second row = +8
  // (inv(k+16) = inv(k)+8 for k<16). Loop-invariant.
  const int klr = ((ktk >> 2) & 1) * 16 + (ktk >> 3) * 4 + (ktk & 3);

  #pragma unroll 1
  for (int pass = 0; pass < 2; ++pass) {
    // heavy tile first; pair sums to 15 -> all blocks cost 68 tile-units
    const int qt     = pass ? (int)blockIdx.x : 15 - (int)blockIdx.x;
    const int q_base = qt * 128 + wave * 16;

    // ---- Q fragments (B-operand of 16x16x32: B[n=col][k=quad*8+j]),
    //      pre-scaled by 1/sqrt(D)*log2(e) ----
    f16x8 qf[4];
    {
      const float* qsrc = Qp + (size_t)(q_base + col) * qrs + quad * 8;
      #pragma unroll
      for (int c = 0; c < 4; ++c) {
        float4 a = *(const float4*)(qsrc + c * 32);
        float4 e = *(const float4*)(qsrc + c * 32 + 4);
        f16x2 p0 = __builtin_amdgcn_cvt_pkrtz(a.x * QSCALE2, a.y * QSCALE2);
        f16x2 p1 = __builtin_amdgcn_cvt_pkrtz(a.z * QSCALE2, a.w * QSCALE2);
        f16x2 p2 = __builtin_amdgcn_cvt_pkrtz(e.x * QSCALE2, e.y * QSCALE2);
        f16x2 p3 = __builtin_amdgcn_cvt_pkrtz(e.z * QSCALE2, e.w * QSCALE2);
        qf[c][0] = p0[0]; qf[c][1] = p0[1]; qf[c][2] = p1[0]; qf[c][3] = p1[1];
        qf[c][4] = p2[0]; qf[c][5] = p2[1]; qf[c][6] = p3[0]; qf[c][7] = p3[1];
      }
    }

    f32x4 oacc[8];
    #pragma unroll
    for (int h = 0; h < 8; ++h) oacc[h] = (f32x4){0.f, 0.f, 0.f, 0.f};
    float m_i = -__builtin_inff();
    float l_i = 0.f;

    const int nt_blk = 4 * qt + 4;                // block-uniform trip count
    const int nt_w   = 4 * qt + (wave >> 1) + 1;  // this wave's causal tiles

    float4 kr[2];
    float  vf[8];

    // prologue: global loads for tile 0
    #pragma unroll
    for (int ro = 0; ro < 2; ++ro)
      kr[ro] = *(const float4*)(Kp + (size_t)(ktk + ro * 16) * krs + ktd);
    #pragma unroll
    for (int i = 0; i < 8; ++i)
      vf[i] = Vp[(size_t)(vh * 8 + i) * krs + vd];

    for (int kt = 0; kt < nt_blk; ++kt) {
      const int bf = kt & 1;
      f16* kb = smem + bf * KBUF;
      f16* vb = smem + 2 * KBUF + bf * VBUF;

      // ---- stage tile kt from registers (cvt + vectorized LDS writes) ----
      #pragma unroll
      for (int ro = 0; ro < 2; ++ro) {
        f16x2 lo = __builtin_amdgcn_cvt_pkrtz(kr[ro].x, kr[ro].y);
        f16x2 hi = __builtin_amdgcn_cvt_pkrtz(kr[ro].z, kr[ro].w);
        f16x4 v4; v4[0] = lo[0]; v4[1] = lo[1]; v4[2] = hi[0]; v4[3] = hi[1];
        *(f16x4*)(kb + (klr + ro * 8) * KSTRIDE + ktd) = v4;   // permuted row
      }
      {
        f16x2 p0 = __builtin_amdgcn_cvt_pkrtz(vf[0], vf[1]);
        f16x2 p1 = __builtin_amdgcn_cvt_pkrtz(vf[2], vf[3]);
        f16x2 p2 = __builtin_amdgcn_cvt_pkrtz(vf[4], vf[5]);
        f16x2 p3 = __builtin_amdgcn_cvt_pkrtz(vf[6], vf[7]);
        f16x8 v8;
        v8[0] = p0[0]; v8[1] = p0[1]; v8[2] = p1[0]; v8[3] = p1[1];
        v8[4] = p2[0]; v8[5] = p2[1]; v8[6] = p3[0]; v8[7] = p3[1];
        *(f16x8*)(vb + vd * VSTRIDE + vh * 8) = v8;   // Vt[d][k-octet], 16B aligned
      }

      // ---- issue next tile's global loads (latency hides under compute) ----
      if (kt + 1 < nt_blk) {
        const int k0n = (kt + 1) * 32;
        #pragma unroll
        for (int ro = 0; ro < 2; ++ro)
          kr[ro] = *(const float4*)(Kp + (size_t)(k0n + ktk + ro * 16) * krs + ktd);
        #pragma unroll
        for (int i = 0; i < 8; ++i)
          vf[i] = Vp[(size_t)(k0n + vh * 8 + i) * krs + vd];
      }

      __syncthreads();

      if (kt < nt_w) {
        const int k0 = kt * 32;

        // ---- S^T = K Q^T : A = K rows (permuted staging => lane-local
        //      k-order quad*8+r / quad*8+4+r), read pattern unchanged ----
        f32x4 s0 = {0.f, 0.f, 0.f, 0.f}, s1 = {0.f, 0.f, 0.f, 0.f};
        #pragma unroll
        for (int c = 0; c < 4; ++c) {
          f16x8 ka = *(const f16x8*)(kb + col * KSTRIDE + quad * 8 + c * 32);
          s0 = __builtin_amdgcn_mfma_f32_16x16x32_f16(ka, qf[c], s0, 0, 0, 0);
        }
        #pragma unroll
        for (int c = 0; c < 4; ++c) {
          f16x8 ka = *(const f16x8*)(kb + (16 + col) * KSTRIDE + quad * 8 + c * 32);
          s1 = __builtin_amdgcn_mfma_f32_16x16x32_f16(ka, qf[c], s1, 0, 0, 0);
        }

        // ---- causal mask; q = col, s0[r] -> k = quad*8+r, s1[r] -> +4 ----
        const int qrow = q_base + col;
        if (k0 + 31 > q_base) {
          #pragma unroll
          for (int r = 0; r < 4; ++r) {
            if (k0 + quad * 8 + r     > qrow) s0[r] = -__builtin_inff();
            if (k0 + quad * 8 + 4 + r > qrow) s1[r] = -__builtin_inff();
          }
        }

        // ---- online softmax, log2 domain, defer-max (P <= 2^8) ----
        float mx = fmaxf(fmaxf(fmaxf(s0[0], s0[1]), fmaxf(s0[2], s0[3])),
                         fmaxf(fmaxf(s1[0], s1[1]), fmaxf(s1[2], s1[3])));
        mx = fmaxf(mx, __shfl_xor(mx, 16, 64));
        mx = fmaxf(mx, __shfl_xor(mx, 32, 64));

        if (!__all(mx - m_i <= 8.0f)) {   // first tile: +inf -> rescale path
          const float mnew  = fmaxf(m_i, mx);
          const float alpha = fast_exp2(m_i - mnew);   // first tile: 0
          m_i = mnew;
          l_i *= alpha;
          #pragma unroll
          for (int h = 0; h < 8; ++h) {
            oacc[h][0] *= alpha; oacc[h][1] *= alpha;
            oacc[h][2] *= alpha; oacc[h][3] *= alpha;
          }
        }

        float e0[4], e1[4], rs = 0.f;
        #pragma unroll
        for (int r = 0; r < 4; ++r) {
          e0[r] = fast_exp2(s0[r] - m_i);
          e1[r] = fast_exp2(s1[r] - m_i);
          rs += e0[r] + e1[r];
        }
        rs += __shfl_xor(rs, 16, 64);
        rs += __shfl_xor(rs, 32, 64);
        l_i += rs;

        // ---- P^T pack: f16x8 B-operand, k = quad*8 + j ----
        f16x2 a01 = __builtin_amdgcn_cvt_pkrtz(e0[0], e0[1]);
        f16x2 a23 = __builtin_amdgcn_cvt_pkrtz(e0[2], e0[3]);
        f16x2 b01 = __builtin_amdgcn_cvt_pkrtz(e1[0], e1[1]);
        f16x2 b23 = __builtin_amdgcn_cvt_pkrtz(e1[2], e1[3]);
        f16x8 pb;
        pb[0] = a01[0]; pb[1] = a01[1]; pb[2] = a23[0]; pb[3] = a23[1];
        pb[4] = b01[0]; pb[5] = b01[1]; pb[6] = b23[0]; pb[7] = b23[1];

        // ---- O^T += V^T P^T : one 16x16x32 per 16-d block,
        //      A = Vt rows, contiguous f16x8 (ds_read_b128) ----
        #pragma unroll
        for (int h = 0; h < 8; ++h) {
          f16x8 va = *(const f16x8*)(vb + (h * 16 + col) * VSTRIDE + quad * 8);
          oacc[h] = __builtin_amdgcn_mfma_f32_16x16x32_f16(va, pb, oacc[h], 0, 0, 0);
        }
      }
    }

    // ---- epilogue: direct stores (16 x 64B segments per instr) ----
    {
      const float invl = 1.0f / l_i;
      #pragma unroll
      for (int h = 0; h < 8; ++h) {
        float4 o;
        o.x = oacc[h][0] * invl; o.y = oacc[h][1] * invl;
        o.z = oacc[h][2] * invl; o.w = oacc[h][3] * invl;
        *(float4*)(Op + (size_t)(q_base + col) * qrs + h * 16 + quad * 4) = o;
      }
    }
  }
}

extern "C" void kernel_launch(void* const* d_in, const int* in_sizes, int n_in,
                              void* d_out, int out_size, void* d_ws, size_t ws_size,
                              hipStream_t stream) {
  const float* Q = (const float*)d_in[0];
  const float* K = (const float*)d_in[1];
  const float* V = (const float*)d_in[2];
  float* O = (float*)d_out;
  (void)in_sizes; (void)n_in; (void)out_size; (void)d_ws; (void)ws_size;
  dim3 grid(SEQ / 256, BATCH * NHQ);   // 8 x 64: each block does q-tiles {15-i, i}
  attn_fwd<<<grid, dim3(512), 0, stream>>>(Q, K, V, O);
}

// Round 6
// 228.789 us; speedup vs baseline: 3.4253x; 1.0715x over previous
//
#include <hip/hip_runtime.h>

#define SEQ    2048
#define BATCH  2
#define NHQ    32
#define NHKV   8
#define DHEAD  128
// 1/sqrt(128) * log2(e): QK^T logits produced directly in log2 domain,
// so softmax uses raw v_exp_f32 (exp2) with no per-score multiply.
#define QSCALE2 0.12751743f

typedef __fp16 f16;
typedef f16 f16x2 __attribute__((ext_vector_type(2)));
typedef f16 f16x4 __attribute__((ext_vector_type(4)));
typedef f16 f16x8 __attribute__((ext_vector_type(8)));
typedef float f32x4 __attribute__((ext_vector_type(4)));

#define KSTRIDE 136                 // halfs per K-tile row (128 + 8 pad)
#define VSTRIDE 40                  // halfs per Vt row (32 k + 8 pad; 16B-aligned rows)
#define KBUF    (32 * KSTRIDE)      // 4352 halfs
#define VBUF    (128 * VSTRIDE)     // 5120 halfs

static __device__ __forceinline__ float fast_exp2(float x) {
#if __has_builtin(__builtin_amdgcn_exp2f)
  return __builtin_amdgcn_exp2f(x);
#else
  return __builtin_exp2f(x);
#endif
}

// v6 = v5 + XCD-locality block swizzle + s_setprio around MFMA clusters +
// lane-local l accumulator (wave-reduce once in epilogue, not per tile).
// Swizzle: with x-fastest linearization, lid = y*8+x and XCD ~ lid%8 = x.
// Old mapping put the 8 same-bh blocks (sharing the K/V stream) on 8
// DIFFERENT XCDs -> 8x K/V L2 duplication (FETCH 175 MB vs 84 ideal).
// New mapping: bh = x*8 + (y>>3), pair_i = y&7 -> same-bh blocks share x
// (= same XCD); per-XCD K/V set = 2 (b,hkv) pairs = 4 MB ~ one L2.
// l-defer is exact: m_i is wave-uniform, so per-lane partial sums of
// exp2(s - m_i) can be reduced across quads once at the end; rescale
// multiplies the partial by wave-uniform alpha.
// v5 history: PV as one 16x16x32 per d-block via write-side K-row
// permutation inv(k)=((k>>2)&1)*16+(k>>3)*4+(k&3); exp2-domain softmax;
// uniform-cost q-tile pairs {15-i,i}; 8-wave staging; conflict-free V
// column staging; direct epilogue; defer-max. 157 us at round 5.
__global__ __launch_bounds__(512, 4) void attn_fwd(const float* __restrict__ Q,
                                                   const float* __restrict__ K,
                                                   const float* __restrict__ V,
                                                   float* __restrict__ O) {
  // XCD-locality swizzle (perf heuristic only; any mapping is correct)
  const int bh     = (int)blockIdx.x * 8 + ((int)blockIdx.y >> 3);
  const int pair_i = (int)blockIdx.y & 7;
  const int b   = bh >> 5;
  const int hq  = bh & 31;
  const int hkv = hq >> 2;
  const int t    = threadIdx.x;
  const int wave = t >> 6;
  const int lane = t & 63;
  const int col  = lane & 15;
  const int quad = lane >> 4;

  const int qrs = BATCH * NHQ * DHEAD;    // 8192
  const int krs = BATCH * NHKV * DHEAD;   // 2048

  const float* Qp = Q + ((size_t)b * NHQ  + hq ) * DHEAD;
  const float* Kp = K + ((size_t)b * NHKV + hkv) * DHEAD;
  const float* Vp = V + ((size_t)b * NHKV + hkv) * DHEAD;
  float*       Op = O + ((size_t)b * NHQ  + hq ) * DHEAD;

  __shared__ __align__(16) f16 smem[2 * KBUF + 2 * VBUF];  // 37888 B

  // staging coords: K rows via float4 (512 thr -> 8 floats each),
  // V via d-columns (lane=d, walk k) -> transposed write is contiguous
  const int ktk = t >> 5;            // kv row 0..15 (+16 for second row)
  const int ktd = (t & 31) * 4;
  const int vd  = t & 127;           // Vt row (d)
  const int vh  = t >> 7;            // 0..3 -> which k-octet
  // permuted LDS row for K staging: row inv(ktk); second row = +8
  // (inv(k+16) = inv(k)+8 for k<16). Loop-invariant.
  const int klr = ((ktk >> 2) & 1) * 16 + (ktk >> 3) * 4 + (ktk & 3);

  #pragma unroll 1
  for (int pass = 0; pass < 2; ++pass) {
    // heavy tile first; pair sums to 15 -> all blocks cost 68 tile-units
    const int qt     = pass ? pair_i : 15 - pair_i;
    const int q_base = qt * 128 + wave * 16;

    // ---- Q fragments (B-operand of 16x16x32: B[n=col][k=quad*8+j]),
    //      pre-scaled by 1/sqrt(D)*log2(e) ----
    f16x8 qf[4];
    {
      const float* qsrc = Qp + (size_t)(q_base + col) * qrs + quad * 8;
      #pragma unroll
      for (int c = 0; c < 4; ++c) {
        float4 a = *(const float4*)(qsrc + c * 32);
        float4 e = *(const float4*)(qsrc + c * 32 + 4);
        f16x2 p0 = __builtin_amdgcn_cvt_pkrtz(a.x * QSCALE2, a.y * QSCALE2);
        f16x2 p1 = __builtin_amdgcn_cvt_pkrtz(a.z * QSCALE2, a.w * QSCALE2);
        f16x2 p2 = __builtin_amdgcn_cvt_pkrtz(e.x * QSCALE2, e.y * QSCALE2);
        f16x2 p3 = __builtin_amdgcn_cvt_pkrtz(e.z * QSCALE2, e.w * QSCALE2);
        qf[c][0] = p0[0]; qf[c][1] = p0[1]; qf[c][2] = p1[0]; qf[c][3] = p1[1];
        qf[c][4] = p2[0]; qf[c][5] = p2[1]; qf[c][6] = p3[0]; qf[c][7] = p3[1];
      }
    }

    f32x4 oacc[8];
    #pragma unroll
    for (int h = 0; h < 8; ++h) oacc[h] = (f32x4){0.f, 0.f, 0.f, 0.f};
    float m_i = -__builtin_inff();
    float l_i = 0.f;                  // lane-local partial (reduced in epilogue)

    const int nt_blk = 4 * qt + 4;                // block-uniform trip count
    const int nt_w   = 4 * qt + (wave >> 1) + 1;  // this wave's causal tiles

    float4 kr[2];
    float  vf[8];

    // prologue: global loads for tile 0
    #pragma unroll
    for (int ro = 0; ro < 2; ++ro)
      kr[ro] = *(const float4*)(Kp + (size_t)(ktk + ro * 16) * krs + ktd);
    #pragma unroll
    for (int i = 0; i < 8; ++i)
      vf[i] = Vp[(size_t)(vh * 8 + i) * krs + vd];

    for (int kt = 0; kt < nt_blk; ++kt) {
      const int bf = kt & 1;
      f16* kb = smem + bf * KBUF;
      f16* vb = smem + 2 * KBUF + bf * VBUF;

      // ---- stage tile kt from registers (cvt + vectorized LDS writes) ----
      #pragma unroll
      for (int ro = 0; ro < 2; ++ro) {
        f16x2 lo = __builtin_amdgcn_cvt_pkrtz(kr[ro].x, kr[ro].y);
        f16x2 hi = __builtin_amdgcn_cvt_pkrtz(kr[ro].z, kr[ro].w);
        f16x4 v4; v4[0] = lo[0]; v4[1] = lo[1]; v4[2] = hi[0]; v4[3] = hi[1];
        *(f16x4*)(kb + (klr + ro * 8) * KSTRIDE + ktd) = v4;   // permuted row
      }
      {
        f16x2 p0 = __builtin_amdgcn_cvt_pkrtz(vf[0], vf[1]);
        f16x2 p1 = __builtin_amdgcn_cvt_pkrtz(vf[2], vf[3]);
        f16x2 p2 = __builtin_amdgcn_cvt_pkrtz(vf[4], vf[5]);
        f16x2 p3 = __builtin_amdgcn_cvt_pkrtz(vf[6], vf[7]);
        f16x8 v8;
        v8[0] = p0[0]; v8[1] = p0[1]; v8[2] = p1[0]; v8[3] = p1[1];
        v8[4] = p2[0]; v8[5] = p2[1]; v8[6] = p3[0]; v8[7] = p3[1];
        *(f16x8*)(vb + vd * VSTRIDE + vh * 8) = v8;   // Vt[d][k-octet], 16B aligned
      }

      // ---- issue next tile's global loads (latency hides under compute) ----
      if (kt + 1 < nt_blk) {
        const int k0n = (kt + 1) * 32;
        #pragma unroll
        for (int ro = 0; ro < 2; ++ro)
          kr[ro] = *(const float4*)(Kp + (size_t)(k0n + ktk + ro * 16) * krs + ktd);
        #pragma unroll
        for (int i = 0; i < 8; ++i)
          vf[i] = Vp[(size_t)(k0n + vh * 8 + i) * krs + vd];
      }

      __syncthreads();

      if (kt < nt_w) {
        const int k0 = kt * 32;

        // ---- S^T = K Q^T : A = K rows (permuted staging => lane-local
        //      k-order quad*8+r / quad*8+4+r), read pattern unchanged ----
        f32x4 s0 = {0.f, 0.f, 0.f, 0.f}, s1 = {0.f, 0.f, 0.f, 0.f};
        __builtin_amdgcn_s_setprio(1);
        #pragma unroll
        for (int c = 0; c < 4; ++c) {
          f16x8 ka = *(const f16x8*)(kb + col * KSTRIDE + quad * 8 + c * 32);
          s0 = __builtin_amdgcn_mfma_f32_16x16x32_f16(ka, qf[c], s0, 0, 0, 0);
        }
        #pragma unroll
        for (int c = 0; c < 4; ++c) {
          f16x8 ka = *(const f16x8*)(kb + (16 + col) * KSTRIDE + quad * 8 + c * 32);
          s1 = __builtin_amdgcn_mfma_f32_16x16x32_f16(ka, qf[c], s1, 0, 0, 0);
        }
        __builtin_amdgcn_s_setprio(0);

        // ---- causal mask; q = col, s0[r] -> k = quad*8+r, s1[r] -> +4 ----
        const int qrow = q_base + col;
        if (k0 + 31 > q_base) {
          #pragma unroll
          for (int r = 0; r < 4; ++r) {
            if (k0 + quad * 8 + r     > qrow) s0[r] = -__builtin_inff();
            if (k0 + quad * 8 + 4 + r > qrow) s1[r] = -__builtin_inff();
          }
        }

        // ---- online softmax, log2 domain, defer-max (P <= 2^8) ----
        float mx = fmaxf(fmaxf(fmaxf(s0[0], s0[1]), fmaxf(s0[2], s0[3])),
                         fmaxf(fmaxf(s1[0], s1[1]), fmaxf(s1[2], s1[3])));
        mx = fmaxf(mx, __shfl_xor(mx, 16, 64));
        mx = fmaxf(mx, __shfl_xor(mx, 32, 64));

        if (!__all(mx - m_i <= 8.0f)) {   // first tile: +inf -> rescale path
          const float mnew  = fmaxf(m_i, mx);
          const float alpha = fast_exp2(m_i - mnew);   // first tile: 0
          m_i = mnew;
          l_i *= alpha;
          #pragma unroll
          for (int h = 0; h < 8; ++h) {
            oacc[h][0] *= alpha; oacc[h][1] *= alpha;
            oacc[h][2] *= alpha; oacc[h][3] *= alpha;
          }
        }

        float e0[4], e1[4], rs = 0.f;
        #pragma unroll
        for (int r = 0; r < 4; ++r) {
          e0[r] = fast_exp2(s0[r] - m_i);
          e1[r] = fast_exp2(s1[r] - m_i);
          rs += e0[r] + e1[r];
        }
        l_i += rs;                      // lane-local; cross-quad reduce deferred

        // ---- P^T pack: f16x8 B-operand, k = quad*8 + j ----
        f16x2 a01 = __builtin_amdgcn_cvt_pkrtz(e0[0], e0[1]);
        f16x2 a23 = __builtin_amdgcn_cvt_pkrtz(e0[2], e0[3]);
        f16x2 b01 = __builtin_amdgcn_cvt_pkrtz(e1[0], e1[1]);
        f16x2 b23 = __builtin_amdgcn_cvt_pkrtz(e1[2], e1[3]);
        f16x8 pb;
        pb[0] = a01[0]; pb[1] = a01[1]; pb[2] = a23[0]; pb[3] = a23[1];
        pb[4] = b01[0]; pb[5] = b01[1]; pb[6] = b23[0]; pb[7] = b23[1];

        // ---- O^T += V^T P^T : one 16x16x32 per 16-d block,
        //      A = Vt rows, contiguous f16x8 (ds_read_b128) ----
        __builtin_amdgcn_s_setprio(1);
        #pragma unroll
        for (int h = 0; h < 8; ++h) {
          f16x8 va = *(const f16x8*)(vb + (h * 16 + col) * VSTRIDE + quad * 8);
          oacc[h] = __builtin_amdgcn_mfma_f32_16x16x32_f16(va, pb, oacc[h], 0, 0, 0);
        }
        __builtin_amdgcn_s_setprio(0);
      }
    }

    // ---- epilogue: reduce l across quads once, direct stores ----
    {
      float lt = l_i + __shfl_xor(l_i, 16, 64);
      lt += __shfl_xor(lt, 32, 64);
      const float invl = 1.0f / lt;
      #pragma unroll
      for (int h = 0; h < 8; ++h) {
        float4 o;
        o.x = oacc[h][0] * invl; o.y = oacc[h][1] * invl;
        o.z = oacc[h][2] * invl; o.w = oacc[h][3] * invl;
        *(float4*)(Op + (size_t)(q_base + col) * qrs + h * 16 + quad * 4) = o;
      }
    }
  }
}

extern "C" void kernel_launch(void* const* d_in, const int* in_sizes, int n_in,
                              void* d_out, int out_size, void* d_ws, size_t ws_size,
                              hipStream_t stream) {
  const float* Q = (const float*)d_in[0];
  const float* K = (const float*)d_in[1];
  const float* V = (const float*)d_in[2];
  float* O = (float*)d_out;
  (void)in_sizes; (void)n_in; (void)out_size; (void)d_ws; (void)ws_size;
  dim3 grid(SEQ / 256, BATCH * NHQ);   // swizzled: bh = x*8 + (y>>3), i = y&7
  attn_fwd<<<grid, dim3(512), 0, stream>>>(Q, K, V, O);
}